// Round 1
// baseline (138.311 us; speedup 1.0000x reference)
//
#include <hip/hip_runtime.h>
#include <math.h>

// SSIM loss, fused. Images: [16, 3, 512, 512] fp32. Output: scalar fp32.
// Box filter 11x11 separable with zero padding, scale 1/11 per pass
// (matches jax conv with uniform weights).

constexpr int WIN  = 11;
constexpr int PADR = WIN / 2;      // 5
constexpr int OTH  = 32;           // output tile height
constexpr int OTW  = 32;           // output tile width
constexpr int INH  = OTH + WIN - 1; // 42
constexpr int INW  = OTW + WIN - 1; // 42
constexpr int H = 512, W = 512;
constexpr int NPLANES = 16 * 3;    // N*C
constexpr long long NPIX = (long long)NPLANES * H * W; // 12,582,912

__global__ __launch_bounds__(256)
void ssim_tile_kernel(const float* __restrict__ img1,
                      const float* __restrict__ img2,
                      float* __restrict__ partials) {
    __shared__ float s1[INH][INW];
    __shared__ float s2[INH][INW];
    __shared__ float vs[5][OTH][INW];

    const int tid = threadIdx.x;
    const int tx0 = blockIdx.x * OTW;
    const int ty0 = blockIdx.y * OTH;
    const int plane = blockIdx.z;
    const float* __restrict__ p1 = img1 + (size_t)plane * H * W;
    const float* __restrict__ p2 = img2 + (size_t)plane * H * W;

    // ---- stage input tiles (with halo, zero-padded) ----
    for (int i = tid; i < INH * INW; i += 256) {
        const int y = i / INW, x = i % INW;
        const int gy = ty0 + y - PADR;
        const int gx = tx0 + x - PADR;
        float a = 0.0f, b = 0.0f;
        if (gy >= 0 && gy < H && gx >= 0 && gx < W) {
            const int gi = gy * W + gx;
            a = p1[gi];
            b = p2[gi];
        }
        s1[y][x] = a;
        s2[y][x] = b;
    }
    __syncthreads();

    // ---- vertical box pass for 5 quantities ----
    constexpr float inv = 1.0f / (float)WIN;
    for (int i = tid; i < OTH * INW; i += 256) {
        const int y = i / INW, x = i % INW;
        float sa = 0.f, sb = 0.f, saa = 0.f, sbb = 0.f, sab = 0.f;
#pragma unroll
        for (int dy = 0; dy < WIN; ++dy) {
            const float a = s1[y + dy][x];
            const float b = s2[y + dy][x];
            sa += a; sb += b;
            saa += a * a; sbb += b * b; sab += a * b;
        }
        vs[0][y][x] = sa * inv;
        vs[1][y][x] = sb * inv;
        vs[2][y][x] = saa * inv;
        vs[3][y][x] = sbb * inv;
        vs[4][y][x] = sab * inv;
    }
    __syncthreads();

    // ---- horizontal box pass + SSIM map + local sum ----
    const float C1 = 0.01f * 0.01f;
    const float C2 = 0.03f * 0.03f;
    float local = 0.0f;
    for (int i = tid; i < OTH * OTW; i += 256) {
        const int y = i / OTW, x = i % OTW;
        float m1 = 0.f, m2 = 0.f, q11 = 0.f, q22 = 0.f, q12 = 0.f;
#pragma unroll
        for (int dx = 0; dx < WIN; ++dx) {
            m1  += vs[0][y][x + dx];
            m2  += vs[1][y][x + dx];
            q11 += vs[2][y][x + dx];
            q22 += vs[3][y][x + dx];
            q12 += vs[4][y][x + dx];
        }
        m1 *= inv; m2 *= inv; q11 *= inv; q22 *= inv; q12 *= inv;
        const float m1m1 = m1 * m1;
        const float m2m2 = m2 * m2;
        const float m1m2 = m1 * m2;
        const float sig1 = q11 - m1m1;
        const float sig2 = q22 - m2m2;
        const float sig12 = q12 - m1m2;
        const float num = (2.0f * m1m2 + C1) * (2.0f * sig12 + C2);
        const float den = (m1m1 + m2m2 + C1) * (sig1 + sig2 + C2);
        local += num / den;
    }

    // ---- block reduction ----
    for (int off = 32; off > 0; off >>= 1)
        local += __shfl_down(local, off);
    __shared__ float wsum[4];
    const int wave = tid >> 6;
    const int lane = tid & 63;
    if (lane == 0) wsum[wave] = local;
    __syncthreads();
    if (tid == 0) {
        const float t = wsum[0] + wsum[1] + wsum[2] + wsum[3];
        const int bid = (blockIdx.z * gridDim.y + blockIdx.y) * gridDim.x + blockIdx.x;
        partials[bid] = t;
    }
}

__global__ __launch_bounds__(256)
void ssim_reduce_kernel(const float* __restrict__ partials, int n,
                        float* __restrict__ out) {
    double s = 0.0;
    for (int i = threadIdx.x; i < n; i += 256)
        s += (double)partials[i];
    // wave reduce (64 lanes)
    for (int off = 32; off > 0; off >>= 1)
        s += __shfl_down(s, off);
    __shared__ double wsum[4];
    const int wave = threadIdx.x >> 6;
    const int lane = threadIdx.x & 63;
    if (lane == 0) wsum[wave] = s;
    __syncthreads();
    if (threadIdx.x == 0) {
        const double total = wsum[0] + wsum[1] + wsum[2] + wsum[3];
        out[0] = (float)(1.0 - total / (double)NPIX);
    }
}

extern "C" void kernel_launch(void* const* d_in, const int* in_sizes, int n_in,
                              void* d_out, int out_size, void* d_ws, size_t ws_size,
                              hipStream_t stream) {
    const float* img1 = (const float*)d_in[0];
    const float* img2 = (const float*)d_in[1];
    float* out = (float*)d_out;
    float* partials = (float*)d_ws;

    dim3 grid(W / OTW, H / OTH, NPLANES);  // 16 x 16 x 48 = 12288 blocks
    dim3 block(256);
    ssim_tile_kernel<<<grid, block, 0, stream>>>(img1, img2, partials);

    const int nblocks = (W / OTW) * (H / OTH) * NPLANES;
    ssim_reduce_kernel<<<1, 256, 0, stream>>>(partials, nblocks, out);
}

// Round 2
// 81.001 us; speedup vs baseline: 1.7075x; 1.7075x over previous
//
#include <hip/hip_runtime.h>
#include <math.h>

// SSIM loss, fused, sliding-window box filters on (s,d,s^2,d^2) where
// s = a+b, d = a-b. Only 4 filtered quantities are needed:
//   mu1*mu2      = (ms^2 - md^2)/4
//   mu1^2+mu2^2  = (ms^2 + md^2)/2
//   box(ab)      = (box(s^2) - box(d^2))/4
//   box(a2)+box(b2) = (box(s^2) + box(d^2))/2
// Images: [16, 3, 512, 512] fp32. Output: scalar fp32.

constexpr int WIN  = 11;
constexpr int PADR = WIN / 2;        // 5
constexpr int OTH  = 32;             // output tile height
constexpr int OTW  = 32;             // output tile width
constexpr int INH  = OTH + WIN - 1;  // 42
constexpr int INW  = OTW + WIN - 1;  // 42
constexpr int VP   = 43;             // padded row stride (float4s) for V: spreads banks
constexpr int H = 512, W = 512;
constexpr int NPLANES = 16 * 3;
constexpr long long NPIX = (long long)NPLANES * H * W;

__device__ __forceinline__ float ssim_px(float ws, float wd, float wss, float wdd,
                                         float inv) {
    const float C1 = 1e-4f;   // 0.01^2
    const float C2 = 9e-4f;   // 0.03^2
    const float ms = ws * inv, md = wd * inv, qs = wss * inv, qd = wdd * inv;
    const float ms2 = ms * ms, md2 = md * md;
    const float mu12  = 0.25f * (ms2 - md2);   // mu1*mu2
    const float musq  = 0.5f  * (ms2 + md2);   // mu1^2+mu2^2
    const float q12   = 0.25f * (qs - qd);     // box(ab)
    const float qsum  = 0.5f  * (qs + qd);     // box(a^2)+box(b^2)
    const float sig12  = q12 - mu12;
    const float sigsum = qsum - musq;
    const float num = (2.0f * mu12 + C1) * (2.0f * sig12 + C2);
    const float den = (musq + C1) * (sigsum + C2);
    return num * __builtin_amdgcn_rcpf(den);
}

__global__ __launch_bounds__(256)
void ssim_tile_kernel(const float* __restrict__ img1,
                      const float* __restrict__ img2,
                      float* __restrict__ partials) {
    __shared__ float  S[INH][INW];   // a+b
    __shared__ float  D[INH][INW];   // a-b
    __shared__ float4 V[OTH][VP];    // vertical sums of {s, d, s^2, d^2} * (1/11)

    const int tid = threadIdx.x;
    const int tx0 = blockIdx.x * OTW;
    const int ty0 = blockIdx.y * OTH;
    const int plane = blockIdx.z;
    const float* __restrict__ p1 = img1 + (size_t)plane * H * W;
    const float* __restrict__ p2 = img2 + (size_t)plane * H * W;
    constexpr float inv = 1.0f / (float)WIN;

    // ---- stage s = a+b, d = a-b (halo, zero-padded) ----
    for (int i = tid; i < INH * INW; i += 256) {
        const int y = i / INW, x = i % INW;
        const int gy = ty0 + y - PADR;
        const int gx = tx0 + x - PADR;
        float a = 0.0f, b = 0.0f;
        if (gy >= 0 && gy < H && gx >= 0 && gx < W) {
            const int gi = gy * W + gx;
            a = p1[gi];
            b = p2[gi];
        }
        S[y][x] = a + b;
        D[y][x] = a - b;
    }
    __syncthreads();

    // ---- vertical sliding-window pass: 42 cols x 6 row-segments ----
    if (tid < 252) {
        const int col = tid % 42;
        const int y0  = (tid / 42) * 6;   // 0,6,12,18,24,30
        float ss = 0.f, sd = 0.f, sss = 0.f, sdd = 0.f;
#pragma unroll
        for (int r = 0; r < WIN; ++r) {
            const float s = S[y0 + r][col];
            const float d = D[y0 + r][col];
            ss += s; sd += d; sss += s * s; sdd += d * d;
        }
        V[y0][col] = make_float4(ss * inv, sd * inv, sss * inv, sdd * inv);
#pragma unroll
        for (int k = 1; k < 6; ++k) {
            const int y = y0 + k;
            if (y < OTH) {
                const float sn = S[y + WIN - 1][col];
                const float dn = D[y + WIN - 1][col];
                const float so = S[y - 1][col];
                const float dl = D[y - 1][col];
                ss  += sn - so;
                sd  += dn - dl;
                sss += sn * sn - so * so;
                sdd += dn * dn - dl * dl;
                V[y][col] = make_float4(ss * inv, sd * inv, sss * inv, sdd * inv);
            }
        }
    }
    __syncthreads();

    // ---- horizontal sliding-window pass + SSIM: 32 rows x 8 col-segments ----
    const int row = tid & 31;
    const int x0  = (tid >> 5) * 4;
    float ws = 0.f, wd = 0.f, wss = 0.f, wdd = 0.f;
#pragma unroll
    for (int r = 0; r < WIN; ++r) {
        const float4 v = V[row][x0 + r];
        ws += v.x; wd += v.y; wss += v.z; wdd += v.w;
    }
    float local = ssim_px(ws, wd, wss, wdd, inv);
#pragma unroll
    for (int k = 1; k < 4; ++k) {
        const float4 vn = V[row][x0 + k + WIN - 1];
        const float4 vo = V[row][x0 + k - 1];
        ws  += vn.x - vo.x;
        wd  += vn.y - vo.y;
        wss += vn.z - vo.z;
        wdd += vn.w - vo.w;
        local += ssim_px(ws, wd, wss, wdd, inv);
    }

    // ---- block reduction ----
    for (int off = 32; off > 0; off >>= 1)
        local += __shfl_down(local, off);
    __shared__ float wsum[4];
    const int wave = tid >> 6;
    const int lane = tid & 63;
    if (lane == 0) wsum[wave] = local;
    __syncthreads();
    if (tid == 0) {
        const float t = wsum[0] + wsum[1] + wsum[2] + wsum[3];
        const int bid = (blockIdx.z * gridDim.y + blockIdx.y) * gridDim.x + blockIdx.x;
        partials[bid] = t;
    }
}

__global__ __launch_bounds__(256)
void ssim_reduce_kernel(const float* __restrict__ partials, int n,
                        float* __restrict__ out) {
    double s = 0.0;
    for (int i = threadIdx.x; i < n; i += 256)
        s += (double)partials[i];
    for (int off = 32; off > 0; off >>= 1)
        s += __shfl_down(s, off);
    __shared__ double wsum[4];
    const int wave = threadIdx.x >> 6;
    const int lane = threadIdx.x & 63;
    if (lane == 0) wsum[wave] = s;
    __syncthreads();
    if (threadIdx.x == 0) {
        const double total = wsum[0] + wsum[1] + wsum[2] + wsum[3];
        out[0] = (float)(1.0 - total / (double)NPIX);
    }
}

extern "C" void kernel_launch(void* const* d_in, const int* in_sizes, int n_in,
                              void* d_out, int out_size, void* d_ws, size_t ws_size,
                              hipStream_t stream) {
    const float* img1 = (const float*)d_in[0];
    const float* img2 = (const float*)d_in[1];
    float* out = (float*)d_out;
    float* partials = (float*)d_ws;

    dim3 grid(W / OTW, H / OTH, NPLANES);  // 16 x 16 x 48 = 12288 blocks
    dim3 block(256);
    ssim_tile_kernel<<<grid, block, 0, stream>>>(img1, img2, partials);

    const int nblocks = (W / OTW) * (H / OTH) * NPLANES;
    ssim_reduce_kernel<<<1, 256, 0, stream>>>(partials, nblocks, out);
}

// Round 3
// 66.376 us; speedup vs baseline: 2.0838x; 1.2203x over previous
//
#include <hip/hip_runtime.h>
#include <math.h>

// SSIM loss, fused. Vertical box pass goes global->registers (11-deep static
// ring per lane-column), only the 4 vertical sums {s, d, s^2, d^2} round-trip
// through LDS for the horizontal pass. s = a+b, d = a-b reformulation:
//   mu1*mu2         = (ms^2 - md^2)/4
//   mu1^2+mu2^2     = (ms^2 + md^2)/2
//   box(ab)         = (box(s^2) - box(d^2))/4
//   box(a^2)+box(b^2) = (box(s^2) + box(d^2))/2
// Images: [16, 3, 512, 512] fp32. Output: scalar fp32.

constexpr int WIN  = 11;
constexpr int PADR = WIN / 2;        // 5
constexpr int OTH  = 32;             // output tile height
constexpr int OTW  = 32;             // output tile width
constexpr int INW  = OTW + WIN - 1;  // 42 columns (one per lane, lanes 0..41)
constexpr int VP   = 43;             // padded V row stride (float4s)
constexpr int SEGR = 8;              // output rows per wave segment
constexpr int SEGI = SEGR + WIN - 1; // 18 input rows per segment
constexpr int H = 512, W = 512;
constexpr int NPLANES = 16 * 3;
constexpr long long NPIX = (long long)NPLANES * H * W;

__device__ __forceinline__ float ssim_px(float ws, float wd, float wss, float wdd) {
    const float C1 = 1e-4f;   // 0.01^2
    const float C2 = 9e-4f;   // 0.03^2
    const float k1 = 1.0f / 121.0f;          // one box-scale (two passes of 1/11)
    const float ka = 0.25f * k1 * k1;
    const float kb = 0.5f  * k1 * k1;
    const float kc = 0.25f * k1;
    const float kd = 0.5f  * k1;
    const float ws2 = ws * ws, wd2 = wd * wd;
    const float mu12 = ka * (ws2 - wd2);     // mu1*mu2
    const float musq = kb * (ws2 + wd2);     // mu1^2 + mu2^2
    const float q12  = kc * (wss - wdd);     // box(ab)
    const float qsum = kd * (wss + wdd);     // box(a^2) + box(b^2)
    const float sig12  = q12 - mu12;
    const float sigsum = qsum - musq;
    const float num = fmaf(2.0f, mu12, C1) * fmaf(2.0f, sig12, C2);
    const float den = (musq + C1) * (sigsum + C2);
    return num * __builtin_amdgcn_rcpf(den);
}

__global__ __launch_bounds__(256)
void ssim_tile_kernel(const float* __restrict__ img1,
                      const float* __restrict__ img2,
                      float* __restrict__ partials) {
    __shared__ float4 V[OTH][VP];   // raw vertical sums {s, d, s^2, d^2}

    const int tid  = threadIdx.x;
    const int wave = tid >> 6;
    const int lane = tid & 63;
    const int tx0 = blockIdx.x * OTW;
    const int ty0 = blockIdx.y * OTH;
    const int plane = blockIdx.z;
    const float* __restrict__ pa = img1 + (size_t)plane * H * W;
    const float* __restrict__ pb = img2 + (size_t)plane * H * W;

    // ---- vertical pass: wave = 8-row segment, lane = column ----
    if (lane < INW) {
        const int gx  = tx0 + lane - PADR;
        const bool xok = (unsigned)gx < (unsigned)W;
        const int gxc = min(max(gx, 0), W - 1);
        const int gy0 = ty0 + wave * SEGR - PADR;
        const int vrow0 = wave * SEGR;
        const float* __restrict__ ca = pa + gxc;
        const float* __restrict__ cb = pb + gxc;

        float sh[WIN], dh[WIN];
        float ss = 0.f, sd = 0.f, sss = 0.f, sdd = 0.f;

#define VSTEP(r, A, B) {                                                     \
        const int _i = (r) % WIN;                                            \
        const float _s = (A) + (B), _d = (A) - (B);                          \
        ss += _s; sd += _d;                                                  \
        sss = fmaf(_s, _s, sss); sdd = fmaf(_d, _d, sdd);                    \
        if ((r) >= WIN) {                                                    \
            const float _so = sh[_i], _do = dh[_i];                          \
            ss -= _so; sd -= _do;                                            \
            sss = fmaf(-_so, _so, sss); sdd = fmaf(-_do, _do, sdd);          \
        }                                                                    \
        sh[_i] = _s; dh[_i] = _d;                                            \
        if ((r) >= WIN - 1)                                                  \
            V[vrow0 + (r) - (WIN - 1)][lane] = make_float4(ss, sd, sss, sdd);\
    }

        if (ty0 >= PADR && ty0 + OTH + PADR + SEGI - SEGR <= H) {
            // interior: all 18 rows of every segment in-bounds vertically
#pragma unroll
            for (int r = 0; r < SEGI; ++r) {
                float a = ca[(gy0 + r) * W];
                float b = cb[(gy0 + r) * W];
                a = xok ? a : 0.f;
                b = xok ? b : 0.f;
                VSTEP(r, a, b)
            }
        } else {
#pragma unroll
            for (int r = 0; r < SEGI; ++r) {
                const int gy = gy0 + r;
                float a = 0.f, b = 0.f;
                if ((unsigned)gy < (unsigned)H) {   // lane-uniform branch
                    a = ca[gy * W];
                    b = cb[gy * W];
                    a = xok ? a : 0.f;
                    b = xok ? b : 0.f;
                }
                VSTEP(r, a, b)
            }
        }
#undef VSTEP
    }
    __syncthreads();

    // ---- horizontal sliding pass + SSIM: 32 rows x 8 col-groups of 4 ----
    const int row = tid & 31;
    const int x0  = (tid >> 5) * 4;
    float ws = 0.f, wd = 0.f, wss = 0.f, wdd = 0.f;
#pragma unroll
    for (int r = 0; r < WIN; ++r) {
        const float4 v = V[row][x0 + r];
        ws += v.x; wd += v.y; wss += v.z; wdd += v.w;
    }
    float local = ssim_px(ws, wd, wss, wdd);
#pragma unroll
    for (int k = 1; k < 4; ++k) {
        const float4 vn = V[row][x0 + k + WIN - 1];
        const float4 vo = V[row][x0 + k - 1];
        ws  += vn.x - vo.x;
        wd  += vn.y - vo.y;
        wss += vn.z - vo.z;
        wdd += vn.w - vo.w;
        local += ssim_px(ws, wd, wss, wdd);
    }

    // ---- block reduction ----
    for (int off = 32; off > 0; off >>= 1)
        local += __shfl_down(local, off);
    __shared__ float wsum[4];
    if ((tid & 63) == 0) wsum[tid >> 6] = local;
    __syncthreads();
    if (tid == 0) {
        const float t = wsum[0] + wsum[1] + wsum[2] + wsum[3];
        const int bid = (blockIdx.z * gridDim.y + blockIdx.y) * gridDim.x + blockIdx.x;
        partials[bid] = t;
    }
}

__global__ __launch_bounds__(256)
void ssim_reduce_kernel(const float* __restrict__ partials, int n,
                        float* __restrict__ out) {
    double s = 0.0;
    for (int i = threadIdx.x; i < n; i += 256)
        s += (double)partials[i];
    for (int off = 32; off > 0; off >>= 1)
        s += __shfl_down(s, off);
    __shared__ double wsum[4];
    if ((threadIdx.x & 63) == 0) wsum[threadIdx.x >> 6] = s;
    __syncthreads();
    if (threadIdx.x == 0) {
        const double total = wsum[0] + wsum[1] + wsum[2] + wsum[3];
        out[0] = (float)(1.0 - total / (double)NPIX);
    }
}

extern "C" void kernel_launch(void* const* d_in, const int* in_sizes, int n_in,
                              void* d_out, int out_size, void* d_ws, size_t ws_size,
                              hipStream_t stream) {
    const float* img1 = (const float*)d_in[0];
    const float* img2 = (const float*)d_in[1];
    float* out = (float*)d_out;
    float* partials = (float*)d_ws;

    dim3 grid(W / OTW, H / OTH, NPLANES);  // 16 x 16 x 48 = 12288 blocks
    dim3 block(256);
    ssim_tile_kernel<<<grid, block, 0, stream>>>(img1, img2, partials);

    const int nblocks = (W / OTW) * (H / OTH) * NPLANES;
    ssim_reduce_kernel<<<1, 256, 0, stream>>>(partials, nblocks, out);
}

// Round 4
// 44.735 us; speedup vs baseline: 3.0918x; 1.4838x over previous
//
#include <hip/hip_runtime.h>
#include <math.h>

// SSIM loss, fused. Lane-exact tiling: 54 output cols -> INW = 64 input cols,
// one column per lane (no idle lanes). Vertical box pass global->registers
// (static 11-ring), 4 vertical sums {s,d,s^2,d^2} through LDS, horizontal
// sliding pass + SSIM. s = a+b, d = a-b reformulation:
//   mu1*mu2           = (ms^2 - md^2)/4
//   mu1^2+mu2^2       = (ms^2 + md^2)/2
//   box(ab)           = (box(s^2) - box(d^2))/4
//   box(a^2)+box(b^2) = (box(s^2) + box(d^2))/2
// Images: [16, 3, 512, 512] fp32. Output: scalar fp32.

constexpr int WIN  = 11;
constexpr int PADR = WIN / 2;        // 5
constexpr int OTW  = 54;             // output tile width (10 tiles cover 512)
constexpr int INW  = 64;             // input cols = one per lane
constexpr int OTH  = 32;             // output tile height
constexpr int VP   = 67;             // padded V row stride (float4s)
constexpr int SEGR = 8;              // output rows per wave segment
constexpr int SEGI = SEGR + WIN - 1; // 18 input rows per segment
constexpr int GPW  = 7;              // horizontal px per thread (8 groups x 7 = 56 >= 54)
constexpr int H = 512, W = 512;
constexpr int NPLANES = 16 * 3;
constexpr int GRIDX = (W + OTW - 1) / OTW;   // 10
constexpr long long NPIX = (long long)NPLANES * H * W;

__device__ __forceinline__ float ssim_px(float ws, float wd, float wss, float wdd) {
    const float C1 = 1e-4f;   // 0.01^2
    const float C2 = 9e-4f;   // 0.03^2
    const float k1 = 1.0f / 121.0f;          // combined box scale (1/11 twice)
    const float ka = 0.25f * k1 * k1;
    const float kb = 0.5f  * k1 * k1;
    const float kc = 0.25f * k1;
    const float kd = 0.5f  * k1;
    const float ws2 = ws * ws, wd2 = wd * wd;
    const float mu12 = ka * (ws2 - wd2);     // mu1*mu2
    const float musq = kb * (ws2 + wd2);     // mu1^2 + mu2^2
    const float q12  = kc * (wss - wdd);     // box(ab)
    const float qsum = kd * (wss + wdd);     // box(a^2) + box(b^2)
    const float sig12  = q12 - mu12;
    const float sigsum = qsum - musq;
    const float num = fmaf(2.0f, mu12, C1) * fmaf(2.0f, sig12, C2);
    const float den = (musq + C1) * (sigsum + C2);
    return num * __builtin_amdgcn_rcpf(den);
}

__global__ __launch_bounds__(256)
void ssim_tile_kernel(const float* __restrict__ img1,
                      const float* __restrict__ img2,
                      float* __restrict__ partials) {
    __shared__ float4 V[OTH][VP];   // raw vertical sums {s, d, s^2, d^2}

    const int tid  = threadIdx.x;
    const int wave = tid >> 6;
    const int lane = tid & 63;
    const int tx0 = blockIdx.x * OTW;
    const int ty0 = blockIdx.y * OTH;
    const int plane = blockIdx.z;
    const float* __restrict__ pa = img1 + (size_t)plane * H * W;
    const float* __restrict__ pb = img2 + (size_t)plane * H * W;

    // ---- vertical pass: wave = 8-row segment, lane = column (all 64 live) ----
    {
        const int gx  = tx0 + lane - PADR;
        const bool xok = (unsigned)gx < (unsigned)W;
        const int gxc = min(max(gx, 0), W - 1);
        const int gy0 = ty0 + wave * SEGR - PADR;
        const int vrow0 = wave * SEGR;
        const float* __restrict__ ca = pa + gxc;
        const float* __restrict__ cb = pb + gxc;

        float sh[WIN], dh[WIN];
        float ss = 0.f, sd = 0.f, sss = 0.f, sdd = 0.f;

#define VSTEP(r, A, B) {                                                     \
        const int _i = (r) % WIN;                                            \
        const float _s = (A) + (B), _d = (A) - (B);                          \
        ss += _s; sd += _d;                                                  \
        sss = fmaf(_s, _s, sss); sdd = fmaf(_d, _d, sdd);                    \
        if ((r) >= WIN) {                                                    \
            const float _so = sh[_i], _do = dh[_i];                          \
            ss -= _so; sd -= _do;                                            \
            sss = fmaf(-_so, _so, sss); sdd = fmaf(-_do, _do, sdd);          \
        }                                                                    \
        sh[_i] = _s; dh[_i] = _d;                                            \
        if ((r) >= WIN - 1)                                                  \
            V[vrow0 + (r) - (WIN - 1)][lane] = make_float4(ss, sd, sss, sdd);\
    }

        if (gy0 >= 0 && gy0 + SEGI <= H) {
            // interior segment: all 18 rows in-bounds vertically
#pragma unroll
            for (int r = 0; r < SEGI; ++r) {
                float a = ca[(gy0 + r) * W];
                float b = cb[(gy0 + r) * W];
                a = xok ? a : 0.f;
                b = xok ? b : 0.f;
                VSTEP(r, a, b)
            }
        } else {
#pragma unroll
            for (int r = 0; r < SEGI; ++r) {
                const int gy = gy0 + r;
                float a = 0.f, b = 0.f;
                if ((unsigned)gy < (unsigned)H) {   // lane-uniform branch
                    a = ca[gy * W];
                    b = cb[gy * W];
                    a = xok ? a : 0.f;
                    b = xok ? b : 0.f;
                }
                VSTEP(r, a, b)
            }
        }
#undef VSTEP
    }
    // zero the over-run columns (64, 65) so the sliding window can read them
    if (tid < OTH) {
        V[tid][64] = make_float4(0.f, 0.f, 0.f, 0.f);
        V[tid][65] = make_float4(0.f, 0.f, 0.f, 0.f);
    }
    __syncthreads();

    // ---- horizontal sliding pass + SSIM: 32 rows x 8 groups of 7 px ----
    const int row = tid & 31;
    const int x0  = (tid >> 5) * GPW;
    const int gxbase = tx0 + x0;
    float ws = 0.f, wd = 0.f, wss = 0.f, wdd = 0.f;
#pragma unroll
    for (int r = 0; r < WIN; ++r) {
        const float4 v = V[row][x0 + r];
        ws += v.x; wd += v.y; wss += v.z; wdd += v.w;
    }
    float local = 0.0f;
    if (x0 < OTW && gxbase < W)
        local = ssim_px(ws, wd, wss, wdd);
#pragma unroll
    for (int k = 1; k < GPW; ++k) {
        const float4 vn = V[row][x0 + k + WIN - 1];
        const float4 vo = V[row][x0 + k - 1];
        ws  += vn.x - vo.x;
        wd  += vn.y - vo.y;
        wss += vn.z - vo.z;
        wdd += vn.w - vo.w;
        if (x0 + k < OTW && gxbase + k < W)
            local += ssim_px(ws, wd, wss, wdd);
    }

    // ---- block reduction ----
    for (int off = 32; off > 0; off >>= 1)
        local += __shfl_down(local, off);
    __shared__ float wsum[4];
    if ((tid & 63) == 0) wsum[tid >> 6] = local;
    __syncthreads();
    if (tid == 0) {
        const float t = wsum[0] + wsum[1] + wsum[2] + wsum[3];
        const int bid = (blockIdx.z * gridDim.y + blockIdx.y) * gridDim.x + blockIdx.x;
        partials[bid] = t;
    }
}

__global__ __launch_bounds__(1024)
void ssim_reduce_kernel(const float4* __restrict__ partials4, int n4,
                        float* __restrict__ out) {
    double s = 0.0;
    for (int i = threadIdx.x; i < n4; i += 1024) {
        const float4 p = partials4[i];
        s += (double)p.x + (double)p.y + (double)p.z + (double)p.w;
    }
    for (int off = 32; off > 0; off >>= 1)
        s += __shfl_down(s, off);
    __shared__ double wsum[16];
    if ((threadIdx.x & 63) == 0) wsum[threadIdx.x >> 6] = s;
    __syncthreads();
    if (threadIdx.x == 0) {
        double total = 0.0;
        for (int w = 0; w < 16; ++w) total += wsum[w];
        out[0] = (float)(1.0 - total / (double)NPIX);
    }
}

extern "C" void kernel_launch(void* const* d_in, const int* in_sizes, int n_in,
                              void* d_out, int out_size, void* d_ws, size_t ws_size,
                              hipStream_t stream) {
    const float* img1 = (const float*)d_in[0];
    const float* img2 = (const float*)d_in[1];
    float* out = (float*)d_out;
    float* partials = (float*)d_ws;

    dim3 grid(GRIDX, H / OTH, NPLANES);  // 10 x 16 x 48 = 7680 blocks
    dim3 block(256);
    ssim_tile_kernel<<<grid, block, 0, stream>>>(img1, img2, partials);

    const int nblocks = GRIDX * (H / OTH) * NPLANES;   // 7680, divisible by 4
    ssim_reduce_kernel<<<1, 1024, 0, stream>>>((const float4*)partials,
                                               nblocks / 4, out);
}

// Round 6
// 44.516 us; speedup vs baseline: 3.1070x; 1.0049x over previous
//
#include <hip/hip_runtime.h>
#include <math.h>

// SSIM loss, fused. Lane-exact tiling (54 out cols -> 64 input cols, one per
// lane). Vertical box pass global->registers (static 11-ring, fp32), vertical
// sums {s,d,s^2,d^2} stored PACKED F16 in LDS (halves LDS size & pipe cycles;
// occupancy cap 16 -> 32 waves/CU). Horizontal sliding in packed f16
// (v_pk_add_f16), unpacked to fp32 per output px for the SSIM rational.
//   mu1*mu2           = (ms^2 - md^2)/4      s = a+b, d = a-b
//   mu1^2+mu2^2       = (ms^2 + md^2)/2
//   box(ab)           = (box(s^2) - box(d^2))/4
//   box(a^2)+box(b^2) = (box(s^2) + box(d^2))/2
// Images: [16, 3, 512, 512] fp32. Output: scalar fp32.

typedef __fp16 half2_t __attribute__((ext_vector_type(2)));
typedef __fp16 half4_t __attribute__((ext_vector_type(4)));

constexpr int WIN  = 11;
constexpr int PADR = WIN / 2;        // 5
constexpr int OTW  = 54;             // output tile width (10 tiles cover 512)
constexpr int OTH  = 32;             // output tile height
constexpr int VP   = 67;             // padded V row stride (half4 units, 536 B/row)
constexpr int SEGR = 8;              // output rows per wave segment
constexpr int SEGI = SEGR + WIN - 1; // 18 input rows per segment
constexpr int GPW  = 7;              // horizontal px per thread group
constexpr int H = 512, W = 512;
constexpr int NPLANES = 16 * 3;
constexpr int GRIDX = (W + OTW - 1) / OTW;   // 10
constexpr long long NPIX = (long long)NPLANES * H * W;

__device__ __forceinline__ half4_t pack4(float a, float b, float c, float d) {
    const half2_t lo = __builtin_amdgcn_cvt_pkrtz(a, b);
    const half2_t hi = __builtin_amdgcn_cvt_pkrtz(c, d);
    half4_t r;
    r[0] = lo[0]; r[1] = lo[1]; r[2] = hi[0]; r[3] = hi[1];
    return r;
}

__device__ __forceinline__ float ssim_px(float ws, float wd, float wss, float wdd) {
    const float C1 = 1e-4f;   // 0.01^2
    const float C2 = 9e-4f;   // 0.03^2
    const float k1 = 1.0f / 121.0f;          // combined box scale (1/11 twice)
    const float ka = 0.25f * k1 * k1;
    const float kb = 0.5f  * k1 * k1;
    const float kc = 0.25f * k1;
    const float kd = 0.5f  * k1;
    const float ws2 = ws * ws, wd2 = wd * wd;
    const float mu12 = ka * (ws2 - wd2);     // mu1*mu2
    const float musq = kb * (ws2 + wd2);     // mu1^2 + mu2^2
    const float q12  = kc * (wss - wdd);     // box(ab)
    const float qsum = kd * (wss + wdd);     // box(a^2) + box(b^2)
    const float sig12  = q12 - mu12;
    const float sigsum = qsum - musq;
    const float num = fmaf(2.0f, mu12, C1) * fmaf(2.0f, sig12, C2);
    const float den = (musq + C1) * (sigsum + C2);
    return num * __builtin_amdgcn_rcpf(den);
}

__device__ __forceinline__ float ssim_h(half2_t alo, half2_t ahi) {
    return ssim_px((float)alo[0], (float)alo[1], (float)ahi[0], (float)ahi[1]);
}

// Vertical box pass for one wave: 18 input rows -> 8 V rows, lane = column.
template<bool XE, bool YE>
__device__ __forceinline__ void vpass(const float* __restrict__ ca,
                                      const float* __restrict__ cb,
                                      int gy0, bool xok, int vrow0, int lane,
                                      half4_t (*V)[VP]) {
    float sh[WIN], dh[WIN];
    float ss = 0.f, sd = 0.f, sss = 0.f, sdd = 0.f;
#pragma unroll
    for (int r = 0; r < SEGI; ++r) {
        float a, b;
        if (YE) {
            const int gy = gy0 + r;
            a = 0.f; b = 0.f;
            if ((unsigned)gy < (unsigned)H) {   // wave-uniform branch
                a = ca[gy * W];
                b = cb[gy * W];
            }
        } else {
            a = ca[(gy0 + r) * W];
            b = cb[(gy0 + r) * W];
        }
        if (XE) {
            a = xok ? a : 0.f;
            b = xok ? b : 0.f;
        }
        const int i = r % WIN;                  // compile-time (unrolled)
        const float s = a + b, d = a - b;
        ss += s; sd += d;
        sss = fmaf(s, s, sss); sdd = fmaf(d, d, sdd);
        if (r >= WIN) {
            const float so = sh[i], dl = dh[i];
            ss -= so; sd -= dl;
            sss = fmaf(-so, so, sss); sdd = fmaf(-dl, dl, sdd);
        }
        sh[i] = s; dh[i] = d;
        if (r >= WIN - 1)
            V[vrow0 + r - (WIN - 1)][lane] = pack4(ss, sd, sss, sdd);
    }
}

__global__ __launch_bounds__(256, 8)
void ssim_tile_kernel(const float* __restrict__ img1,
                      const float* __restrict__ img2,
                      float* __restrict__ partials) {
    __shared__ half4_t V[OTH][VP];   // raw vertical sums, packed f16

    const int tid  = threadIdx.x;
    const int wave = tid >> 6;
    const int lane = tid & 63;
    const int tx0 = blockIdx.x * OTW;
    const int ty0 = blockIdx.y * OTH;
    const int plane = blockIdx.z;
    const float* __restrict__ pa = img1 + (size_t)plane * H * W;
    const float* __restrict__ pb = img2 + (size_t)plane * H * W;

    // ---- vertical pass: wave = 8-row segment, lane = column (all 64 live) ----
    {
        const int gx  = tx0 + lane - PADR;
        const bool xok = (unsigned)gx < (unsigned)W;
        const int gxc = min(max(gx, 0), W - 1);
        const int gy0 = ty0 + wave * SEGR - PADR;
        const int vrow0 = wave * SEGR;
        const bool xe = (blockIdx.x == 0) || (blockIdx.x == GRIDX - 1);
        const bool ye = (gy0 < 0) || (gy0 + SEGI > H);
        const float* __restrict__ ca = pa + gxc;
        const float* __restrict__ cb = pb + gxc;
        if (!xe) {
            if (!ye) vpass<false, false>(ca, cb, gy0, xok, vrow0, lane, V);
            else     vpass<false, true >(ca, cb, gy0, xok, vrow0, lane, V);
        } else {
            if (!ye) vpass<true, false>(ca, cb, gy0, xok, vrow0, lane, V);
            else     vpass<true, true >(ca, cb, gy0, xok, vrow0, lane, V);
        }
    }
    __syncthreads();

    // ---- horizontal sliding pass (packed f16) + SSIM: 32 rows x 8 groups ----
    // Group 7 covers only 5 valid px (49..53); its k=5,6 reads hit cols 64/65
    // (allocated, garbage) but those outputs are masked off.
    const int row = tid & 31;
    const int x0  = (tid >> 5) * GPW;
    const int gxb = tx0 + x0;
    half2_t alo = {(__fp16)0, (__fp16)0};
    half2_t ahi = alo;
#pragma unroll
    for (int r = 0; r < WIN; ++r) {
        const half4_t v = V[row][x0 + r];
        const half2_t vl = {v[0], v[1]};
        const half2_t vh = {v[2], v[3]};
        alo += vl; ahi += vh;
    }
    float local = 0.0f;
    if (gxb < W)   // x0 <= 49 < OTW always; W-check only bites in the last block
        local = ssim_h(alo, ahi);
#pragma unroll
    for (int k = 1; k < GPW; ++k) {
        const half4_t vn = V[row][x0 + k + WIN - 1];
        const half4_t vo = V[row][x0 + k - 1];
        const half2_t dl = {(__fp16)(vn[0] - vo[0]), (__fp16)(vn[1] - vo[1])};
        const half2_t dh = {(__fp16)(vn[2] - vo[2]), (__fp16)(vn[3] - vo[3])};
        alo += dl; ahi += dh;
        if (x0 + k < OTW && gxb + k < W)
            local += ssim_h(alo, ahi);
    }

    // ---- wave reduction, one partial per wave ----
    for (int off = 32; off > 0; off >>= 1)
        local += __shfl_down(local, off);
    if ((tid & 63) == 0) {
        const int bid = (blockIdx.z * gridDim.y + blockIdx.y) * gridDim.x + blockIdx.x;
        partials[bid * 4 + wave] = local;
    }
}

__global__ __launch_bounds__(1024)
void ssim_reduce_kernel(const float4* __restrict__ partials4, int n4,
                        float* __restrict__ out) {
    double s = 0.0;
    for (int i = threadIdx.x; i < n4; i += 1024) {
        const float4 p = partials4[i];
        s += (double)p.x + (double)p.y + (double)p.z + (double)p.w;
    }
    for (int off = 32; off > 0; off >>= 1)
        s += __shfl_down(s, off);
    __shared__ double wsum[16];
    if ((threadIdx.x & 63) == 0) wsum[threadIdx.x >> 6] = s;
    __syncthreads();
    if (threadIdx.x == 0) {
        double total = 0.0;
        for (int w = 0; w < 16; ++w) total += wsum[w];
        out[0] = (float)(1.0 - total / (double)NPIX);
    }
}

extern "C" void kernel_launch(void* const* d_in, const int* in_sizes, int n_in,
                              void* d_out, int out_size, void* d_ws, size_t ws_size,
                              hipStream_t stream) {
    const float* img1 = (const float*)d_in[0];
    const float* img2 = (const float*)d_in[1];
    float* out = (float*)d_out;
    float* partials = (float*)d_ws;

    dim3 grid(GRIDX, H / OTH, NPLANES);  // 10 x 16 x 48 = 7680 blocks
    dim3 block(256);
    ssim_tile_kernel<<<grid, block, 0, stream>>>(img1, img2, partials);

    const int npart = GRIDX * (H / OTH) * NPLANES * 4;   // 30720, /4 = 7680
    ssim_reduce_kernel<<<1, 1024, 0, stream>>>((const float4*)partials,
                                               npart / 4, out);
}

// Round 7
// 38.601 us; speedup vs baseline: 3.5831x; 1.1532x over previous
//
#include <hip/hip_runtime.h>
#include <math.h>

// SSIM loss, fused. Round 7: halve VMEM wave-instruction count via float2
// (dwordx2) loads - each lane owns TWO columns. INW=128 cols/block, OTW=116.
// Vertical box pass global->registers (static 11-ring x 2 cols, fp32),
// vertical sums {s,d,s^2,d^2} packed f16 in LDS, horizontal sliding in
// packed f16. s = a+b, d = a-b reformulation:
//   mu1*mu2           = (ms^2 - md^2)/4
//   mu1^2+mu2^2       = (ms^2 + md^2)/2
//   box(ab)           = (box(s^2) - box(d^2))/4
//   box(a^2)+box(b^2) = (box(s^2) + box(d^2))/2
// Images: [16, 3, 512, 512] fp32. Output: scalar fp32.

typedef __fp16 half2_t __attribute__((ext_vector_type(2)));
typedef __fp16 half4_t __attribute__((ext_vector_type(4)));

constexpr int WIN  = 11;
constexpr int OTW  = 116;            // output tile width (5 tiles cover 512)
constexpr int INW  = 128;            // input cols = 2 per lane
constexpr int OTH  = 32;             // output tile height
constexpr int VP   = 131;            // V row stride in half4 (1048 B: 2-way-free col reads)
constexpr int SEGR = 8;              // output rows per wave segment
constexpr int SEGI = SEGR + WIN - 1; // 18 input rows per segment
constexpr int GPW  = 15;             // horizontal px per thread (8 groups x 15 >= 116)
constexpr int H = 512, W = 512;
constexpr int NPLANES = 16 * 3;
constexpr int GRIDX = (W + OTW - 1) / OTW;   // 5
constexpr long long NPIX = (long long)NPLANES * H * W;

__device__ __forceinline__ half4_t pack4(float a, float b, float c, float d) {
    const half2_t lo = __builtin_amdgcn_cvt_pkrtz(a, b);
    const half2_t hi = __builtin_amdgcn_cvt_pkrtz(c, d);
    half4_t r;
    r[0] = lo[0]; r[1] = lo[1]; r[2] = hi[0]; r[3] = hi[1];
    return r;
}

__device__ __forceinline__ float ssim_px(float ws, float wd, float wss, float wdd) {
    const float C1 = 1e-4f;   // 0.01^2
    const float C2 = 9e-4f;   // 0.03^2
    const float k1 = 1.0f / 121.0f;          // combined box scale (1/11 twice)
    const float ka = 0.25f * k1 * k1;
    const float kb = 0.5f  * k1 * k1;
    const float kc = 0.25f * k1;
    const float kd = 0.5f  * k1;
    const float ws2 = ws * ws, wd2 = wd * wd;
    const float mu12 = ka * (ws2 - wd2);     // mu1*mu2
    const float musq = kb * (ws2 + wd2);     // mu1^2 + mu2^2
    const float q12  = kc * (wss - wdd);     // box(ab)
    const float qsum = kd * (wss + wdd);     // box(a^2) + box(b^2)
    const float sig12  = q12 - mu12;
    const float sigsum = qsum - musq;
    const float num = fmaf(2.0f, mu12, C1) * fmaf(2.0f, sig12, C2);
    const float den = (musq + C1) * (sigsum + C2);
    return num * __builtin_amdgcn_rcpf(den);
}

__device__ __forceinline__ float ssim_h(half2_t alo, half2_t ahi) {
    return ssim_px((float)alo[0], (float)alo[1], (float)ahi[0], (float)ahi[1]);
}

// Vertical box pass, one wave: 18 input rows -> 8 V rows, lane = 2 columns.
template<bool XE, bool YE>
__device__ __forceinline__ void vpass(const float* __restrict__ ca,
                                      const float* __restrict__ cb,
                                      int gy0, bool xok0, bool xok1,
                                      int vrow0, int lane, half4_t (*V)[VP]) {
    float sh0[WIN], dh0[WIN], sh1[WIN], dh1[WIN];
    float ss0 = 0.f, sd0 = 0.f, sss0 = 0.f, sdd0 = 0.f;
    float ss1 = 0.f, sd1 = 0.f, sss1 = 0.f, sdd1 = 0.f;
#pragma unroll
    for (int r = 0; r < SEGI; ++r) {
        float a0, a1, b0, b1;
        if (YE) {
            const int gy = gy0 + r;
            a0 = a1 = b0 = b1 = 0.f;
            if ((unsigned)gy < (unsigned)H) {     // wave-uniform branch
                const float2 va = *(const float2*)(ca + (size_t)gy * W);
                const float2 vb = *(const float2*)(cb + (size_t)gy * W);
                a0 = va.x; a1 = va.y; b0 = vb.x; b1 = vb.y;
            }
        } else {
            const float2 va = *(const float2*)(ca + (size_t)(gy0 + r) * W);
            const float2 vb = *(const float2*)(cb + (size_t)(gy0 + r) * W);
            a0 = va.x; a1 = va.y; b0 = vb.x; b1 = vb.y;
        }
        if (XE) {
            a0 = xok0 ? a0 : 0.f;  b0 = xok0 ? b0 : 0.f;
            a1 = xok1 ? a1 : 0.f;  b1 = xok1 ? b1 : 0.f;
        }
        const int i = r % WIN;                    // compile-time (unrolled)
        const float s0 = a0 + b0, d0 = a0 - b0;
        const float s1 = a1 + b1, d1 = a1 - b1;
        ss0 += s0; sd0 += d0; sss0 = fmaf(s0, s0, sss0); sdd0 = fmaf(d0, d0, sdd0);
        ss1 += s1; sd1 += d1; sss1 = fmaf(s1, s1, sss1); sdd1 = fmaf(d1, d1, sdd1);
        if (r >= WIN) {
            const float so0 = sh0[i], do0 = dh0[i];
            const float so1 = sh1[i], do1 = dh1[i];
            ss0 -= so0; sd0 -= do0; sss0 = fmaf(-so0, so0, sss0); sdd0 = fmaf(-do0, do0, sdd0);
            ss1 -= so1; sd1 -= do1; sss1 = fmaf(-so1, so1, sss1); sdd1 = fmaf(-do1, do1, sdd1);
        }
        sh0[i] = s0; dh0[i] = d0; sh1[i] = s1; dh1[i] = d1;
        if (r >= WIN - 1) {
            const int vr = vrow0 + r - (WIN - 1);
            V[vr][2 * lane]     = pack4(ss0, sd0, sss0, sdd0);
            V[vr][2 * lane + 1] = pack4(ss1, sd1, sss1, sdd1);
        }
    }
}

__global__ __launch_bounds__(256, 4)
void ssim_tile_kernel(const float* __restrict__ img1,
                      const float* __restrict__ img2,
                      float* __restrict__ partials) {
    __shared__ half4_t V[OTH][VP];   // raw vertical sums, packed f16
    __shared__ float wsum[4];

    const int tid  = threadIdx.x;
    const int wave = tid >> 6;
    const int lane = tid & 63;
    const int tx0 = blockIdx.x * OTW;
    const int ty0 = blockIdx.y * OTH;
    const int plane = blockIdx.z;
    const float* __restrict__ pa = img1 + (size_t)plane * H * W;
    const float* __restrict__ pb = img2 + (size_t)plane * H * W;

    // ---- vertical pass: wave = 8-row segment, lane = 2 columns ----
    {
        // V col j <-> image col tx0 - 6 + j; lane l owns j = 2l, 2l+1.
        const int gxl = tx0 - 6 + 2 * lane;
        const bool xok0 = (unsigned)gxl < (unsigned)W;
        const bool xok1 = (unsigned)(gxl + 1) < (unsigned)W;
        const int gc = min(max(gxl, 0), W - 2);   // even -> 8B-aligned float2
        const int gy0 = ty0 + wave * SEGR - (WIN / 2);
        const int vrow0 = wave * SEGR;
        const bool xe = (blockIdx.x == 0) || (blockIdx.x == GRIDX - 1);
        const bool ye = (gy0 < 0) || (gy0 + SEGI > H);
        const float* __restrict__ ca = pa + gc;
        const float* __restrict__ cb = pb + gc;
        if (!xe) {
            if (!ye) vpass<false, false>(ca, cb, gy0, xok0, xok1, vrow0, lane, V);
            else     vpass<false, true >(ca, cb, gy0, xok0, xok1, vrow0, lane, V);
        } else {
            if (!ye) vpass<true, false>(ca, cb, gy0, xok0, xok1, vrow0, lane, V);
            else     vpass<true, true >(ca, cb, gy0, xok0, xok1, vrow0, lane, V);
        }
    }
    // zero over-run V cols 128..130 (group-7 sliding reads, outputs masked)
    if (tid < 96) {
        const int row = tid / 3, c = 128 + tid % 3;
        half4_t z; z[0] = (__fp16)0; z[1] = (__fp16)0; z[2] = (__fp16)0; z[3] = (__fp16)0;
        V[row][c] = z;
    }
    __syncthreads();

    // ---- horizontal sliding pass (packed f16) + SSIM: 32 rows x 8 groups ----
    // Output px (tile-rel x) reads V cols j = x+1 .. x+11.
    const int row = tid & 31;
    const int x0  = (tid >> 5) * GPW;
    const int gxb = tx0 + x0;
    half2_t alo = {(__fp16)0, (__fp16)0};
    half2_t ahi = alo;
#pragma unroll
    for (int r = 0; r < WIN; ++r) {
        const half4_t v = V[row][x0 + 1 + r];
        const half2_t vl = {v[0], v[1]};
        const half2_t vh = {v[2], v[3]};
        alo += vl; ahi += vh;
    }
    float local = 0.0f;
    if (gxb < W)
        local = ssim_h(alo, ahi);
#pragma unroll
    for (int k = 1; k < GPW; ++k) {
        const half4_t vn = V[row][x0 + k + WIN];   // new col j = (x0+k)+11
        const half4_t vo = V[row][x0 + k];         // old col j = (x0+k-1)+1
        const half2_t dl = {(__fp16)(vn[0] - vo[0]), (__fp16)(vn[1] - vo[1])};
        const half2_t dh = {(__fp16)(vn[2] - vo[2]), (__fp16)(vn[3] - vo[3])};
        alo += dl; ahi += dh;
        if (x0 + k < OTW && gxb + k < W)
            local += ssim_h(alo, ahi);
    }

    // ---- block reduction, one partial per block ----
    for (int off = 32; off > 0; off >>= 1)
        local += __shfl_down(local, off);
    if ((tid & 63) == 0) wsum[wave] = local;
    __syncthreads();
    if (tid == 0) {
        const int bid = (blockIdx.z * gridDim.y + blockIdx.y) * gridDim.x + blockIdx.x;
        partials[bid] = wsum[0] + wsum[1] + wsum[2] + wsum[3];
    }
}

__global__ __launch_bounds__(1024)
void ssim_reduce_kernel(const float4* __restrict__ partials4, int n4,
                        float* __restrict__ out) {
    double s = 0.0;
    for (int i = threadIdx.x; i < n4; i += 1024) {
        const float4 p = partials4[i];
        s += (double)p.x + (double)p.y + (double)p.z + (double)p.w;
    }
    for (int off = 32; off > 0; off >>= 1)
        s += __shfl_down(s, off);
    __shared__ double wsum[16];
    if ((threadIdx.x & 63) == 0) wsum[threadIdx.x >> 6] = s;
    __syncthreads();
    if (threadIdx.x == 0) {
        double total = 0.0;
        for (int w = 0; w < 16; ++w) total += wsum[w];
        out[0] = (float)(1.0 - total / (double)NPIX);
    }
}

extern "C" void kernel_launch(void* const* d_in, const int* in_sizes, int n_in,
                              void* d_out, int out_size, void* d_ws, size_t ws_size,
                              hipStream_t stream) {
    const float* img1 = (const float*)d_in[0];
    const float* img2 = (const float*)d_in[1];
    float* out = (float*)d_out;
    float* partials = (float*)d_ws;

    dim3 grid(GRIDX, H / OTH, NPLANES);  // 5 x 16 x 48 = 3840 blocks
    dim3 block(256);
    ssim_tile_kernel<<<grid, block, 0, stream>>>(img1, img2, partials);

    const int nblocks = GRIDX * (H / OTH) * NPLANES;   // 3840, divisible by 4
    ssim_reduce_kernel<<<1, 1024, 0, stream>>>((const float4*)partials,
                                               nblocks / 4, out);
}